// Round 11
// baseline (276.328 us; speedup 1.0000x reference)
//
#include <hip/hip_runtime.h>
#include <math.h>

#define BN 64
#define PN 16800
#define ON 64
#define THRESH 0.35f
#define NEGPOS 7
#define GX 66                  // encode slabs per row (66*256 >= 16800)
#define NBLK (BN * GX)         // 4224 partial slots
#define NBP 1024               // bp blocks (64 b * 16 blocks of 4 truths)
#define NCELL 256              // 16x16 spatial cells
#define NCB 66                 // count/scatter blocks (66*256 >= 16800)
#define EPSW 0.0009765625f     // 1/1024: absorbs float rounding in window math
#define IOUF 0.3499f           // conservative 0.35 with 1e-4 slack >> float ulp
#define TAILT 104              // threads with tail work in select (416/4)

__device__ __forceinline__ unsigned f2key(float f) {
  unsigned u = __float_as_uint(f);
  return (u & 0x80000000u) ? ~u : (u | 0x80000000u);
}
__device__ __forceinline__ float key2f(unsigned k) {
  unsigned u = (k & 0x80000000u) ? (k & 0x7FFFFFFFu) : ~k;
  return __uint_as_float(u);
}
__device__ __forceinline__ float sl1(float d) {
  float a = fabsf(d);
  return (a < 1.f) ? 0.5f * a * a : a - 0.5f;
}

// ====== K0: wide count — per-block histograms (no memset, no global atomics) ======
__global__ void k_count(const float* __restrict__ priors,
                        unsigned char* __restrict__ pcell,
                        unsigned* __restrict__ bhist,
                        float* __restrict__ gmaxblk) {
  __shared__ unsigned lcnt[NCELL];
  __shared__ float swm[4], swh[4];
  int tid = threadIdx.x;
  int bid = blockIdx.x;
  lcnt[tid] = 0;
  __syncthreads();
  int p = bid * 256 + tid;
  float mw = 0.f, mh = 0.f;
  if (p < PN) {
    float4 pr = reinterpret_cast<const float4*>(priors)[p];
    int cx = (int)(pr.x * 16.f); cx = cx < 0 ? 0 : (cx > 15 ? 15 : cx);
    int cy = (int)(pr.y * 16.f); cy = cy < 0 ? 0 : (cy > 15 ? 15 : cy);
    int cell = cy * 16 + cx;
    pcell[p] = (unsigned char)cell;
    atomicAdd(&lcnt[cell], 1u);
    mw = pr.z * 0.5f;
    mh = pr.w * 0.5f;
  }
#pragma unroll
  for (int off = 32; off; off >>= 1) {
    mw = fmaxf(mw, __shfl_xor(mw, off));
    mh = fmaxf(mh, __shfl_xor(mh, off));
  }
  if ((tid & 63) == 0) { swm[tid >> 6] = mw; swh[tid >> 6] = mh; }
  __syncthreads();
  if (tid == 0) {
    gmaxblk[bid * 2] = fmaxf(fmaxf(swm[0], swm[1]), fmaxf(swm[2], swm[3]));
    gmaxblk[bid * 2 + 1] = fmaxf(fmaxf(swh[0], swh[1]), fmaxf(swh[2], swh[3]));
  }
  bhist[bid * NCELL + tid] = lcnt[tid];
}

// ====== K1: wide scatter (blocks 0..65) + per-(b,cell) truth masks (66..129) ======
__global__ void k_scatter(const float* __restrict__ priors,
                          const float* __restrict__ targets,
                          const unsigned char* __restrict__ pcell,
                          const unsigned* __restrict__ bhist,
                          const float* __restrict__ gmaxblk,
                          unsigned* __restrict__ gmax,
                          float4* __restrict__ sbox,
                          int* __restrict__ sorig,
                          int* __restrict__ cellOff,
                          unsigned long long* __restrict__ tmask) {
  int bid = blockIdx.x;
  int tid = threadIdx.x;
  if (bid < NCB) {
    __shared__ unsigned tmp[NCELL];
    __shared__ unsigned sbase[NCELL];
    __shared__ unsigned lcnt[NCELL];
    // sum per-block histograms; this block's base within cell = earlier blocks
    unsigned tot = 0, mybase = 0;
#pragma unroll 4
    for (int b2 = 0; b2 < NCB; b2++) {
      unsigned h = bhist[b2 * NCELL + tid];
      if (b2 < bid) mybase += h;
      tot += h;
    }
    tmp[tid] = tot;
    lcnt[tid] = 0;
    __syncthreads();
    // inclusive ladder scan over 256 bins (redundant per block; counts final)
    for (int off = 1; off < NCELL; off <<= 1) {
      unsigned v = (tid >= off) ? tmp[tid - off] : 0u;
      __syncthreads();
      tmp[tid] += v;
      __syncthreads();
    }
    unsigned excl = tmp[tid] - tot;
    sbase[tid] = excl + mybase;
    if (bid == 0) {
      cellOff[tid] = (int)excl;
      if (tid == 0) {
        cellOff[NCELL] = PN;
        float MW = 0.f, MH = 0.f;
        for (int i = 0; i < NCB; i++) {
          MW = fmaxf(MW, gmaxblk[2 * i]);
          MH = fmaxf(MH, gmaxblk[2 * i + 1]);
        }
        gmax[0] = __float_as_uint(MW);   // consumed by k_bp (next launch)
        gmax[1] = __float_as_uint(MH);
      }
    }
    __syncthreads();
    int p = bid * 256 + tid;
    if (p < PN) {
      int cell = pcell[p];
      unsigned lrank = atomicAdd(&lcnt[cell], 1u);
      int slot = (int)(sbase[cell] + lrank);
      float4 pr = reinterpret_cast<const float4*>(priors)[p];
      float px1 = pr.x - pr.z * 0.5f, py1 = pr.y - pr.w * 0.5f;
      float px2 = pr.x + pr.z * 0.5f, py2 = pr.y + pr.w * 0.5f;
      sbox[slot] = make_float4(px1, py1, px2, py2);
      sorig[slot] = p;
    }
  } else {
    // ---- masks role: b = bid - NCB; thread = cell ----
    // bt consumes t ONLY when pos (max IoU >= 0.35), so the mask only needs
    // truths that can reach IoU >= 0.35 with some prior in this cell.
    int b = bid - NCB;
    __shared__ float4 tb[ON];
    if (tid < ON) {
      const float* tg = &targets[((long)b * ON + tid) * 15];
      tb[tid] = make_float4(tg[0], tg[1], tg[2], tg[3]);
    }
    __syncthreads();
    float MW = 0.f, MH = 0.f;
    for (int i = 0; i < NCB; i++) {
      MW = fmaxf(MW, gmaxblk[2 * i]);
      MH = fmaxf(MH, gmaxblk[2 * i + 1]);
    }
    int cx = tid & 15, cy = tid >> 4;
    float cxl = (float)cx * 0.0625f, cxh = (float)(cx + 1) * 0.0625f;
    float cyl = (float)cy * 0.0625f, cyh = (float)(cy + 1) * 0.0625f;
    float pmaxa = 4.f * MW * MH;
    unsigned long long m = 0ull;
    for (int t = 0; t < ON; t++) {
      float4 a = tb[t];
      float wt = a.z - a.x, ht = a.w - a.y;
      float at = wt * ht;
      float need = IOUF * at;
      float wmin = need / fminf(ht, 2.f * MH);
      float hmin = need / fminf(wt, 2.f * MW);
      float wx0 = a.x + wmin - MW - EPSW, wx1 = a.z - wmin + MW + EPSW;
      float wy0 = a.y + hmin - MH - EPSW, wy1 = a.w - hmin + MH + EPSW;
      bool ok = (pmaxa >= need) &&
                (cxh > wx0) && (cxl < wx1) &&
                (cyh > wy0) && (cyl < wy1);
      if (ok) m |= (1ull << t);
    }
    tmask[b * NCELL + tid] = m;
  }
}

// ====== K2: pruned best-prior only (one wave per (b, truth)) ======
__global__ void k_bp(const float* __restrict__ targets,
                     const float4* __restrict__ sbox,
                     const int* __restrict__ sorig,
                     const int* __restrict__ cellOff,
                     const unsigned* __restrict__ gmax,
                     unsigned long long* __restrict__ bpp) {
  int bid = blockIdx.x;
  int tid = threadIdx.x;
  int lane = tid & 63, wv = tid >> 6;
  int b = bid >> 4;
  int t = ((bid & 15) << 2) + wv;
  const float* tg = &targets[((long)b * ON + t) * 15];
  float ax1 = tg[0], ay1 = tg[1], ax2 = tg[2], ay2 = tg[3];
  float aa = (ax2 - ax1) * (ay2 - ay1);
  float MW = __uint_as_float(gmax[0]), MH = __uint_as_float(gmax[1]);
  int xlo = (int)floorf((ax1 - MW - EPSW) * 16.f); xlo = xlo < 0 ? 0 : (xlo > 15 ? 15 : xlo);
  int xhi = (int)floorf((ax2 + MW + EPSW) * 16.f); xhi = xhi < 0 ? 0 : (xhi > 15 ? 15 : xhi);
  int ylo = (int)floorf((ay1 - MH - EPSW) * 16.f); ylo = ylo < 0 ? 0 : (ylo > 15 ? 15 : ylo);
  int yhi = (int)floorf((ay2 + MH + EPSW) * 16.f); yhi = yhi < 0 ? 0 : (yhi > 15 ? 15 : yhi);
  // default = prior 0 with IoU 0 (matches reference argmax over all-zero overlaps)
  float bi = 0.f, bu = 1.f; int bp = 0;
  for (int cy = ylo; cy <= yhi; cy++) {
    int s0 = cellOff[cy * 16 + xlo];
    int s1 = cellOff[cy * 16 + xhi + 1];
    for (int s = s0 + lane; s < s1; s += 64) {
      float4 pr = sbox[s];
      int op = sorig[s];
      float ab2 = (pr.z - pr.x) * (pr.w - pr.y);
      float lx = fmaxf(ax1, pr.x), ly = fmaxf(ay1, pr.y);
      float rx = fminf(ax2, pr.z), ry = fminf(ay2, pr.w);
      float w = fmaxf(rx - lx, 0.f), h = fmaxf(ry - ly, 0.f);
      float inter = w * h;
      float uni = aa + ab2 - inter;
      float A = inter * bu, C = bi * uni;
      if (A > C || (A == C && op < bp)) { bi = inter; bu = uni; bp = op; }
    }
  }
#pragma unroll
  for (int off = 1; off < 64; off <<= 1) {
    float oi = __shfl_xor(bi, off), ou = __shfl_xor(bu, off);
    int op = __shfl_xor(bp, off);
    float A = oi * bu, C = bi * ou;
    if (A > C || (A == C && op < bp)) { bi = oi; bu = ou; bp = op; }
  }
  if (lane == 0) {
    float q = bi / bu;
    bpp[(long)b * ON + t] = ((unsigned long long)f2key(q) << 32) | (unsigned)(~bp);
  }
}

// ========= K3: fused best-truth + encode + scatter-override + partials =========
__global__ void k_encode(const float* __restrict__ loc_data,
                         const float* __restrict__ conf_data,
                         const float* __restrict__ landm_data,
                         const float* __restrict__ priors,
                         const float* __restrict__ targets,
                         const unsigned char* __restrict__ pcell,
                         const unsigned long long* __restrict__ tmask,
                         const unsigned long long* __restrict__ bpp,
                         float* __restrict__ lossc, unsigned char* __restrict__ posf,
                         float* __restrict__ part_l, float* __restrict__ part_lm,
                         int* __restrict__ np_part, int* __restrict__ np1_part) {
  int b = blockIdx.y;
  int p = blockIdx.x * 256 + threadIdx.x;
  int bid = b * GX + blockIdx.x;
  __shared__ float4 tgs4[ON * 15 / 4];
  __shared__ float4 tb[ON];
  __shared__ float ta[ON];
  __shared__ unsigned long long smask[NCELL];
  __shared__ int ovr[256];
  float* tgs = (float*)tgs4;
  if (threadIdx.x < ON * 15 / 4)
    tgs4[threadIdx.x] = reinterpret_cast<const float4*>(targets + (long)b * ON * 15)[threadIdx.x];
  smask[threadIdx.x] = tmask[b * NCELL + threadIdx.x];
  if (threadIdx.x < ON) {
    const float* tg = &targets[((long)b * ON + threadIdx.x) * 15];
    float4 bx = make_float4(tg[0], tg[1], tg[2], tg[3]);
    tb[threadIdx.x] = bx;
    ta[threadIdx.x] = (bx.z - bx.x) * (bx.w - bx.y);
  }
  ovr[threadIdx.x] = -1;
  __syncthreads();
  if (threadIdx.x < ON) {
    int t = threadIdx.x;
    unsigned long long best = bpp[(long)b * ON + t];
    float q = key2f((unsigned)(best >> 32));
    int qp = (int)(~(unsigned)best);
    int s0 = blockIdx.x * 256;
    if (qp >= s0 && qp < s0 + 256) {
      int valid = (q >= 0.2f) ? 1 : 0;
      atomicMax(&ovr[qp - s0], (t << 1) | valid);
    }
  }
  __syncthreads();

  float sum_l = 0.f, sum_lm = 0.f;
  int cp = 0, cp1 = 0;
  if (p < PN) {
    float4 pr = reinterpret_cast<const float4*>(priors)[p];
    float px1 = pr.x - pr.z * 0.5f, py1 = pr.y - pr.w * 0.5f;
    float px2 = pr.x + pr.z * 0.5f, py2 = pr.y + pr.w * 0.5f;
    float ab2 = (px2 - px1) * (py2 - py1);
    unsigned long long m = smask[pcell[p]];
    // 2-way unrolled mask walk (overlaps LDS gathers + IoU chains);
    // compare order t0-then-t1 preserves reference first-max tie semantics
    float bi = 0.f, bu = 1.f; int t = 0;
    while (m) {
      int t0 = __builtin_ctzll(m); m &= m - 1;
      float4 a0 = tb[t0]; float aa0 = ta[t0];
      if (m) {
        int t1 = __builtin_ctzll(m); m &= m - 1;
        float4 a1 = tb[t1]; float aa1 = ta[t1];
        float lx0 = fmaxf(a0.x, px1), ly0 = fmaxf(a0.y, py1);
        float rx0 = fminf(a0.z, px2), ry0 = fminf(a0.w, py2);
        float w0 = fmaxf(rx0 - lx0, 0.f), h0 = fmaxf(ry0 - ly0, 0.f);
        float in0 = w0 * h0, un0 = aa0 + ab2 - in0;
        float lx1 = fmaxf(a1.x, px1), ly1 = fmaxf(a1.y, py1);
        float rx1 = fminf(a1.z, px2), ry1 = fminf(a1.w, py2);
        float w1 = fmaxf(rx1 - lx1, 0.f), h1 = fmaxf(ry1 - ly1, 0.f);
        float in1 = w1 * h1, un1 = aa1 + ab2 - in1;
        if (in0 * bu > bi * un0) { bi = in0; bu = un0; t = t0; }
        if (in1 * bu > bi * un1) { bi = in1; bu = un1; t = t1; }
      } else {
        float lx = fmaxf(a0.x, px1), ly = fmaxf(a0.y, py1);
        float rx = fminf(a0.z, px2), ry = fminf(a0.w, py2);
        float w2 = fmaxf(rx - lx, 0.f), h2 = fmaxf(ry - ly, 0.f);
        float inter = w2 * h2;
        float uni = aa0 + ab2 - inter;
        if (inter * bu > bi * uni) { bi = inter; bu = uni; t = t0; }
      }
    }
    bool pos = (bi / bu) >= THRESH;
    int o = ovr[threadIdx.x];
    if (o >= 0) { t = o >> 1; if (o & 1) pos = true; }
    const float* tg = &tgs[t * 15];
    float label = tg[14];
    bool pos1 = pos && (label > 0.f);
    if (pos) {
      float rz = 1.0f / pr.z, rw = 1.0f / pr.w;
      float m0 = tg[0], m1 = tg[1], m2 = tg[2], m3 = tg[3];
      float g0 = ((m0 + m2) * 0.5f - pr.x) * rz * 10.f;
      float g1 = ((m1 + m3) * 0.5f - pr.y) * rw * 10.f;
      float g2 = __logf((m2 - m0) * rz) * 5.f;
      float g3 = __logf((m3 - m1) * rw) * 5.f;
      const float* ld = &loc_data[((long)b * PN + p) * 4];
      sum_l = sl1(ld[0] - g0) + sl1(ld[1] - g1) + sl1(ld[2] - g2) + sl1(ld[3] - g3);
      cp = 1;
      if (pos1) {
        const float* lm = &landm_data[((long)b * PN + p) * 10];
#pragma unroll
        for (int i = 0; i < 5; i++) {
          float gx = (tg[4 + 2 * i] - pr.x) * rz * 10.f;
          float gy = (tg[5 + 2 * i] - pr.y) * rw * 10.f;
          sum_lm += sl1(lm[2 * i] - gx) + sl1(lm[2 * i + 1] - gy);
        }
        cp1 = 1;
      }
    }
    float2 c2 = reinterpret_cast<const float2*>(conf_data)[(long)b * PN + p];
    float mx = fmaxf(c2.x, c2.y);
    float lse = mx + __logf(__expf(c2.x - mx) + __expf(c2.y - mx));
    lossc[b * PN + p] = lse - (pos ? c2.y : c2.x);
    posf[b * PN + p] = pos ? 1 : 0;
  }
  for (int off = 32; off; off >>= 1) {
    sum_l += __shfl_down(sum_l, off);
    sum_lm += __shfl_down(sum_lm, off);
    cp += __shfl_down(cp, off);
    cp1 += __shfl_down(cp1, off);
  }
  __shared__ float sl4[4], slm4[4];
  __shared__ int sp4[4], sp14[4];
  int w = threadIdx.x >> 6;
  if ((threadIdx.x & 63) == 0) { sl4[w] = sum_l; slm4[w] = sum_lm; sp4[w] = cp; sp14[w] = cp1; }
  __syncthreads();
  if (threadIdx.x == 0) {
    part_l[bid] = sl4[0] + sl4[1] + sl4[2] + sl4[3];
    part_lm[bid] = slm4[0] + slm4[1] + slm4[2] + slm4[3];
    np_part[bid] = sp4[0] + sp4[1] + sp4[2] + sp4[3];
    np1_part[bid] = sp14[0] + sp14[1] + sp14[2] + sp14[3];
  }
}

// ===== K4: top-k via 64-bit composite keys (value<<32 | ~index) — keys are
// DISTINCT so count(K >= T) == k exactly and tie machinery vanishes.
// Coalesced interleaved loads; 16-way multi-probe search (<=17 iterations). =====
__global__ void __launch_bounds__(1024) k_select(const float* __restrict__ lossc,
                                                 const unsigned char* __restrict__ posf,
                                                 const int* __restrict__ np_part,
                                                 const int* __restrict__ np1_part,
                                                 const float* __restrict__ part_l,
                                                 const float* __restrict__ part_lm,
                                                 float* __restrict__ rout) {
  int b = blockIdx.x;
  int tid = threadIdx.x;
  int lane = tid & 63;
  int wv = tid >> 6;
  __shared__ int s_np, s_rnp1;
  __shared__ float s_rsl, s_rslm;
  __shared__ unsigned long long s_lo, s_hi;
  __shared__ unsigned fpack[16][8];
  __shared__ float wsum[16];
  const float* row = &lossc[(long)b * PN];
  const unsigned char* prow = &posf[(long)b * PN];

  if (tid == 0) {
    s_np = 0; s_rnp1 = 0; s_rsl = 0.f; s_rslm = 0.f;
    s_lo = 0ull; s_hi = 0xFFFFFFFFFFFFFFFFull;
  }
  __syncthreads();
  if (tid < GX) {
    atomicAdd(&s_np, np_part[b * GX + tid]);
    atomicAdd(&s_rsl, part_l[b * GX + tid]);
    atomicAdd(&s_rslm, part_lm[b * GX + tid]);
    atomicAdd(&s_rnp1, np1_part[b * GX + tid]);
  }

  // interleaved coalesced loads: float4 idx = c*1024 + tid (lane stride 16B)
  const float4* rf4 = reinterpret_cast<const float4*>(row);
  const unsigned* pw = reinterpret_cast<const unsigned*>(prow);
  float4 v4[4];
  unsigned pm[4];
#pragma unroll
  for (int c = 0; c < 4; c++) {
    v4[c] = rf4[c * 1024 + tid];
    pm[c] = pw[c * 1024 + tid];
  }
  bool hasTail = tid < TAILT;
  float4 vt4;
  unsigned pmt = 0;
  if (hasTail) {
    vt4 = rf4[4096 + tid];
    pmt = pw[4096 + tid];
  } else {
    vt4 = make_float4(-1.f, -1.f, -1.f, -1.f);  // key < any real loss key (loss >= 0)
  }
  // composite keys: distinct; order == (value desc, index asc) == ref argsort
  unsigned long long K[20];
#pragma unroll
  for (int c = 0; c < 4; c++) {
    const float* vf = (const float*)&v4[c];
    int e0 = 4 * (c * 1024 + tid);
#pragma unroll
    for (int f = 0; f < 4; f++)
      K[c * 4 + f] = ((unsigned long long)f2key(vf[f]) << 32) | (unsigned)(~(e0 + f));
  }
  {
    const float* vf = (const float*)&vt4;
    int e0 = 4 * (4096 + tid);
#pragma unroll
    for (int f = 0; f < 4; f++)
      K[16 + f] = ((unsigned long long)f2key(vf[f]) << 32) | (unsigned)(~(e0 + f));
  }
  __syncthreads();
  int np = s_np;
  int k = NEGPOS * np;
  if (k > PN - 1) k = PN - 1;
  bool haveNeg = (k > 0);

  unsigned long long T = 0ull;
  if (haveNeg) {
    // invariant: count(K >= lo) >= k (so lo <= k-th largest K < 2^63: no wrap),
    // count(K >= hi+1) < k. 16-way narrowing: width/16 per iter -> <=17 iters.
    for (int it = 0; it < 20; ++it) {
      unsigned long long lo = s_lo, hi = s_hi;
      if (lo >= hi) break;
      unsigned long long step = (hi - lo) / 16ull + 1ull;
      unsigned cnt[15];
#pragma unroll
      for (int j = 0; j < 15; j++) {
        unsigned long long pj = lo + (unsigned long long)(j + 1) * step;
        unsigned c = 0;
#pragma unroll
        for (int e = 0; e < 20; e++) c += (K[e] >= pj) ? 1u : 0u;
        cnt[j] = c;
      }
      unsigned pk[8];
#pragma unroll
      for (int i = 0; i < 7; i++) pk[i] = cnt[2 * i] | (cnt[2 * i + 1] << 16);
      pk[7] = cnt[14];
#pragma unroll
      for (int i = 0; i < 8; i++) {
#pragma unroll
        for (int o = 32; o; o >>= 1) pk[i] += (unsigned)__shfl_down((int)pk[i], o);
      }
      if (lane == 0) {
#pragma unroll
        for (int i = 0; i < 8; i++) fpack[wv][i] = pk[i];
      }
      __syncthreads();
      if (wv == 0) {
        bool q = false;
        if (lane == 0) q = true;                 // probe 0 (= lo) always qualifies
        else if (lane <= 15) {
          int cj = lane - 1;                     // cnt index for probe = lane
          int idx = cj >> 1;
          int sh = (cj & 1) * 16;
          unsigned tot = 0;
          for (int w2 = 0; w2 < 16; w2++) tot += (fpack[w2][idx] >> sh) & 0xFFFFu;
          q = tot >= (unsigned)k;
        }
        unsigned long long mk = __ballot(q) & 0xFFFFull;
        if (lane == 0) {
          int j = 63 - __clzll(mk);              // highest qualifying probe
          unsigned long long nlo = lo + (unsigned long long)j * step;
          unsigned long long nhi = (j < 15) ? (lo + (unsigned long long)(j + 1) * step - 1ull) : hi;
          s_lo = nlo; s_hi = nhi;
        }
      }
      __syncthreads();
    }
    T = s_lo;   // = k-th largest composite key; count(K >= T) == k exactly
  }

  float acc = 0.f;
#pragma unroll
  for (int c = 0; c < 4; c++) {
    const float* vf = (const float*)&v4[c];
#pragma unroll
    for (int f = 0; f < 4; f++) {
      float v = vf[f];
      bool pos = (pm[c] >> (8 * f)) & 1u;
      if (pos) acc += v;
      else if (haveNeg && K[c * 4 + f] >= T) acc += v;
    }
  }
  {
    const float* vf = (const float*)&vt4;
#pragma unroll
    for (int f = 0; f < 4; f++) {
      float v = vf[f];
      bool pos = (pmt >> (8 * f)) & 1u;
      if (pos) acc += v;
      else if (haveNeg && K[16 + f] >= T) acc += v;
    }
  }
#pragma unroll
  for (int o = 32; o; o >>= 1) acc += __shfl_down(acc, o);
  if (lane == 0) wsum[wv] = acc;
  __syncthreads();
  if (tid == 0) {
    float tot = 0.f;
    for (int i = 0; i < 16; i++) tot += wsum[i];
    rout[b * 8 + 0] = tot;
    rout[b * 8 + 1] = s_rsl;
    rout[b * 8 + 2] = s_rslm;
    ((int*)rout)[b * 8 + 3] = np;
    ((int*)rout)[b * 8 + 4] = s_rnp1;
  }
}

// ===== K5: final reduction (1 wave) =====
__global__ void k_final(const float* __restrict__ rout, float* __restrict__ out) {
  int tid = threadIdx.x;  // 64 threads, one per b
  float sc = rout[tid * 8 + 0];
  float sl = rout[tid * 8 + 1];
  float slm = rout[tid * 8 + 2];
  int np = ((const int*)rout)[tid * 8 + 3];
  int np1 = ((const int*)rout)[tid * 8 + 4];
#pragma unroll
  for (int o = 32; o; o >>= 1) {
    sc += __shfl_down(sc, o);
    sl += __shfl_down(sl, o);
    slm += __shfl_down(slm, o);
    np += __shfl_down(np, o);
    np1 += __shfl_down(np1, o);
  }
  if (tid == 0) {
    float N = fmaxf((float)np, 1.f);
    float N1 = fmaxf((float)np1, 1.f);
    out[0] = sl / N;
    out[1] = sc / N;
    out[2] = slm / N1;
  }
}

extern "C" void kernel_launch(void* const* d_in, const int* in_sizes, int n_in,
                              void* d_out, int out_size, void* d_ws, size_t ws_size,
                              hipStream_t stream) {
  const float* loc_data = (const float*)d_in[0];
  const float* conf_data = (const float*)d_in[1];
  const float* landm_data = (const float*)d_in[2];
  const float* priors = (const float*)d_in[3];
  const float* targets = (const float*)d_in[4];
  float* out = (float*)d_out;

  char* ws = (char*)d_ws;
  size_t off = 0;
  float* lossc = (float*)(ws + off); off += (size_t)BN * PN * 4;              // 4.30 MB
  unsigned char* posf = (unsigned char*)(ws + off); off += (size_t)BN * PN;   // 1.07 MB
  off = (off + 15) & ~(size_t)15;
  unsigned long long* bpp = (unsigned long long*)(ws + off); off += (size_t)BN * ON * 8;
  float* part_l = (float*)(ws + off); off += NBLK * 4;
  float* part_lm = (float*)(ws + off); off += NBLK * 4;
  int* np_part = (int*)(ws + off); off += NBLK * 4;
  int* np1_part = (int*)(ws + off); off += NBLK * 4;
  float4* sbox = (float4*)(ws + off); off += (size_t)PN * 16;
  int* sorig = (int*)(ws + off); off += (size_t)PN * 4;
  unsigned char* pcell = (unsigned char*)(ws + off); off += (size_t)PN;
  off = (off + 15) & ~(size_t)15;
  int* cellOff = (int*)(ws + off); off += 260 * 4;
  unsigned long long* tmask = (unsigned long long*)(ws + off); off += (size_t)BN * NCELL * 8;
  off = (off + 15) & ~(size_t)15;
  unsigned* bhist = (unsigned*)(ws + off); off += (size_t)NCB * NCELL * 4;    // 67.6 KB
  float* gmaxblk = (float*)(ws + off); off += (size_t)NCB * 2 * 4;
  unsigned* gmax = (unsigned*)(ws + off); off += 16;
  float* rout = (float*)(ws + off); off += (size_t)BN * 8 * 4;
  // total ~6.2 MB

  k_count<<<NCB, 256, 0, stream>>>(priors, pcell, bhist, gmaxblk);
  k_scatter<<<NCB + BN, 256, 0, stream>>>(priors, targets, pcell, bhist, gmaxblk, gmax,
                                          sbox, sorig, cellOff, tmask);
  k_bp<<<NBP, 256, 0, stream>>>(targets, sbox, sorig, cellOff, gmax, bpp);
  dim3 gbp(GX, BN);
  k_encode<<<gbp, 256, 0, stream>>>(loc_data, conf_data, landm_data, priors, targets,
                                    pcell, tmask, bpp, lossc, posf,
                                    part_l, part_lm, np_part, np1_part);
  k_select<<<BN, 1024, 0, stream>>>(lossc, posf, np_part, np1_part, part_l, part_lm,
                                    rout);
  k_final<<<1, 64, 0, stream>>>(rout, out);
}

// Round 12
// 187.511 us; speedup vs baseline: 1.4737x; 1.4737x over previous
//
#include <hip/hip_runtime.h>
#include <math.h>

#define BN 64
#define PN 16800
#define ON 64
#define THRESH 0.35f
#define NEGPOS 7
#define GX 66                  // encode/bt slabs per row (66*256 >= 16800)
#define NBLK (BN * GX)         // 4224 partial slots
#define NBP 1024               // bp blocks (64 b * 16 blocks of 4 truths)
#define NBTT (BN * GX)         // 4224 bt blocks
#define NCELL 256              // 16x16 spatial cells
#define NCB 66                 // count/scatter blocks (66*256 >= 16800)
#define EPSW 0.0009765625f     // 1/1024: absorbs float rounding in window math
#define NBINS 4096
#define MAXM 4096
#define TAILT 104              // threads with tail work in select (416/4)

struct GAcc {
  unsigned ticket;
  float sl, slm, sc;
  int np, np1;
  unsigned pad0, pad1;
};

__device__ __forceinline__ unsigned f2key(float f) {
  unsigned u = __float_as_uint(f);
  return (u & 0x80000000u) ? ~u : (u | 0x80000000u);
}
__device__ __forceinline__ float key2f(unsigned k) {
  unsigned u = (k & 0x80000000u) ? (k & 0x7FFFFFFFu) : ~k;
  return __uint_as_float(u);
}
__device__ __forceinline__ float sl1(float d) {
  float a = fabsf(d);
  return (a < 1.f) ? 0.5f * a * a : a - 0.5f;
}

// ====== K0: wide count — per-block histograms (no memset, no global atomics) ======
__global__ void k_count(const float* __restrict__ priors,
                        unsigned char* __restrict__ pcell,
                        unsigned* __restrict__ bhist,
                        float* __restrict__ gmaxblk,
                        GAcc* __restrict__ gacc) {
  __shared__ unsigned lcnt[NCELL];
  __shared__ float swm[4], swh[4];
  int tid = threadIdx.x;
  int bid = blockIdx.x;
  lcnt[tid] = 0;
  if (bid == 0 && tid < 8) ((unsigned*)gacc)[tid] = 0;
  __syncthreads();
  int p = bid * 256 + tid;
  float mw = 0.f, mh = 0.f;
  if (p < PN) {
    float4 pr = reinterpret_cast<const float4*>(priors)[p];
    int cx = (int)(pr.x * 16.f); cx = cx < 0 ? 0 : (cx > 15 ? 15 : cx);
    int cy = (int)(pr.y * 16.f); cy = cy < 0 ? 0 : (cy > 15 ? 15 : cy);
    int cell = cy * 16 + cx;
    pcell[p] = (unsigned char)cell;
    atomicAdd(&lcnt[cell], 1u);
    mw = pr.z * 0.5f;
    mh = pr.w * 0.5f;
  }
#pragma unroll
  for (int off = 32; off; off >>= 1) {
    mw = fmaxf(mw, __shfl_xor(mw, off));
    mh = fmaxf(mh, __shfl_xor(mh, off));
  }
  if ((tid & 63) == 0) { swm[tid >> 6] = mw; swh[tid >> 6] = mh; }
  __syncthreads();
  if (tid == 0) {
    gmaxblk[bid * 2] = fmaxf(fmaxf(swm[0], swm[1]), fmaxf(swm[2], swm[3]));
    gmaxblk[bid * 2 + 1] = fmaxf(fmaxf(swh[0], swh[1]), fmaxf(swh[2], swh[3]));
  }
  bhist[bid * NCELL + tid] = lcnt[tid];
}

// ====== K1: wide scatter (blocks 0..65) + per-(b,cell) truth masks (66..129) ======
__global__ void k_scatter(const float* __restrict__ priors,
                          const float* __restrict__ targets,
                          const unsigned char* __restrict__ pcell,
                          const unsigned* __restrict__ bhist,
                          const float* __restrict__ gmaxblk,
                          unsigned* __restrict__ gmax,
                          float4* __restrict__ sbox,
                          int* __restrict__ sorig,
                          int* __restrict__ scell,
                          int* __restrict__ inv,
                          int* __restrict__ cellOff,
                          unsigned long long* __restrict__ tmask) {
  int bid = blockIdx.x;
  int tid = threadIdx.x;
  if (bid < NCB) {
    __shared__ unsigned tmp[NCELL];
    __shared__ unsigned sbase[NCELL];
    __shared__ unsigned lcnt[NCELL];
    // sum per-block histograms; this block's base within cell = earlier blocks
    unsigned tot = 0, mybase = 0;
#pragma unroll 4
    for (int b2 = 0; b2 < NCB; b2++) {
      unsigned h = bhist[b2 * NCELL + tid];
      if (b2 < bid) mybase += h;
      tot += h;
    }
    tmp[tid] = tot;
    lcnt[tid] = 0;
    __syncthreads();
    // inclusive ladder scan over 256 bins (redundant per block; counts final)
    for (int off = 1; off < NCELL; off <<= 1) {
      unsigned v = (tid >= off) ? tmp[tid - off] : 0u;
      __syncthreads();
      tmp[tid] += v;
      __syncthreads();
    }
    unsigned excl = tmp[tid] - tot;
    sbase[tid] = excl + mybase;
    if (bid == 0) {
      cellOff[tid] = (int)excl;
      if (tid == 0) {
        cellOff[NCELL] = PN;
        float MW = 0.f, MH = 0.f;
        for (int i = 0; i < NCB; i++) {
          MW = fmaxf(MW, gmaxblk[2 * i]);
          MH = fmaxf(MH, gmaxblk[2 * i + 1]);
        }
        gmax[0] = __float_as_uint(MW);   // consumed by k_pair (next launch)
        gmax[1] = __float_as_uint(MH);
      }
    }
    __syncthreads();
    int p = bid * 256 + tid;
    if (p < PN) {
      int cell = pcell[p];
      unsigned lrank = atomicAdd(&lcnt[cell], 1u);
      int slot = (int)(sbase[cell] + lrank);
      float4 pr = reinterpret_cast<const float4*>(priors)[p];
      float px1 = pr.x - pr.z * 0.5f, py1 = pr.y - pr.w * 0.5f;
      float px2 = pr.x + pr.z * 0.5f, py2 = pr.y + pr.w * 0.5f;
      sbox[slot] = make_float4(px1, py1, px2, py2);
      sorig[slot] = p;
      scell[slot] = cell;
      inv[p] = slot;
    }
  } else {
    // ---- masks role: b = bid - NCB; thread = cell (r5-proven window) ----
    int b = bid - NCB;
    __shared__ float4 tb[ON];
    if (tid < ON) {
      const float* tg = &targets[((long)b * ON + tid) * 15];
      tb[tid] = make_float4(tg[0], tg[1], tg[2], tg[3]);
    }
    __syncthreads();
    float MW = 0.f, MH = 0.f;
    for (int i = 0; i < NCB; i++) {
      MW = fmaxf(MW, gmaxblk[2 * i]);
      MH = fmaxf(MH, gmaxblk[2 * i + 1]);
    }
    int cx = tid & 15, cy = tid >> 4;
    // tight window: 1 cell + max prior half-extent + ulp guard (EPSW >> ulp)
    float x0 = (float)cx * 0.0625f - MW - EPSW, x1 = (float)(cx + 1) * 0.0625f + MW + EPSW;
    float y0 = (float)cy * 0.0625f - MH - EPSW, y1 = (float)(cy + 1) * 0.0625f + MH + EPSW;
    unsigned long long m = 0ull;
    for (int t = 0; t < ON; t++) {
      float4 a = tb[t];
      if (x0 < a.z && x1 > a.x && y0 < a.w && y1 > a.y) m |= (1ull << t);
    }
    tmask[b * NCELL + tid] = m;
  }
}

// ====== K2: pruned best-prior (per truth) + pruned best-truth (per prior) ======
__global__ void k_pair(const float* __restrict__ targets,
                       const float4* __restrict__ sbox,
                       const int* __restrict__ sorig,
                       const int* __restrict__ scell,
                       const int* __restrict__ cellOff,
                       const unsigned* __restrict__ gmax,
                       const unsigned long long* __restrict__ tmask,
                       unsigned char* __restrict__ btpack,
                       unsigned long long* __restrict__ bpp) {
  int bid = blockIdx.x;
  int tid = threadIdx.x;

  if (bid < NBP) {
    // ---- best-prior role: one wave per (b, truth), scan candidate cell rows ----
    int lane = tid & 63, wv = tid >> 6;
    int b = bid >> 4;
    int t = ((bid & 15) << 2) + wv;
    const float* tg = &targets[((long)b * ON + t) * 15];
    float ax1 = tg[0], ay1 = tg[1], ax2 = tg[2], ay2 = tg[3];
    float aa = (ax2 - ax1) * (ay2 - ay1);
    float MW = __uint_as_float(gmax[0]), MH = __uint_as_float(gmax[1]);
    int xlo = (int)floorf((ax1 - MW - EPSW) * 16.f); xlo = xlo < 0 ? 0 : (xlo > 15 ? 15 : xlo);
    int xhi = (int)floorf((ax2 + MW + EPSW) * 16.f); xhi = xhi < 0 ? 0 : (xhi > 15 ? 15 : xhi);
    int ylo = (int)floorf((ay1 - MH - EPSW) * 16.f); ylo = ylo < 0 ? 0 : (ylo > 15 ? 15 : ylo);
    int yhi = (int)floorf((ay2 + MH + EPSW) * 16.f); yhi = yhi < 0 ? 0 : (yhi > 15 ? 15 : yhi);
    // default = prior 0 with IoU 0 (matches reference argmax over all-zero overlaps)
    float bi = 0.f, bu = 1.f; int bp = 0;
    for (int cy = ylo; cy <= yhi; cy++) {
      int s0 = cellOff[cy * 16 + xlo];
      int s1 = cellOff[cy * 16 + xhi + 1];
      for (int s = s0 + lane; s < s1; s += 64) {
        float4 pr = sbox[s];
        int op = sorig[s];
        float ab2 = (pr.z - pr.x) * (pr.w - pr.y);
        float lx = fmaxf(ax1, pr.x), ly = fmaxf(ay1, pr.y);
        float rx = fminf(ax2, pr.z), ry = fminf(ay2, pr.w);
        float w = fmaxf(rx - lx, 0.f), h = fmaxf(ry - ly, 0.f);
        float inter = w * h;
        float uni = aa + ab2 - inter;
        float A = inter * bu, C = bi * uni;
        if (A > C || (A == C && op < bp)) { bi = inter; bu = uni; bp = op; }
      }
    }
#pragma unroll
    for (int off = 1; off < 64; off <<= 1) {
      float oi = __shfl_xor(bi, off), ou = __shfl_xor(bu, off);
      int op = __shfl_xor(bp, off);
      float A = oi * bu, C = bi * ou;
      if (A > C || (A == C && op < bp)) { bi = oi; bu = ou; bp = op; }
    }
    if (lane == 0) {
      float q = bi / bu;
      bpp[(long)b * ON + t] = ((unsigned long long)f2key(q) << 32) | (unsigned)(~bp);
    }
  } else {
    // ---- best-truth role: one thread per sorted prior, wave-union truth mask
    // (wave-uniform walk => every LDS read is a broadcast, no divergence) ----
    int id2 = bid - NBP;
    int b = id2 / GX;
    int slab = id2 - b * GX;
    int s = slab * 256 + tid;
    bool valid = s < PN;
    int sc = valid ? s : PN - 1;
    __shared__ float4 tb[ON];
    __shared__ float ta[ON];
    if (tid < ON) {
      const float* tg = &targets[((long)b * ON + tid) * 15];
      float4 bx = make_float4(tg[0], tg[1], tg[2], tg[3]);
      tb[tid] = bx;
      ta[tid] = (bx.z - bx.x) * (bx.w - bx.y);
    }
    __syncthreads();
    float4 pr = sbox[sc];
    float ab2 = (pr.z - pr.x) * (pr.w - pr.y);
    unsigned long long um = valid ? tmask[b * NCELL + scell[sc]] : 0ull;
#pragma unroll
    for (int off = 1; off < 64; off <<= 1) um |= __shfl_xor(um, off);
    unsigned mlo = (unsigned)__builtin_amdgcn_readfirstlane((int)(unsigned)um);
    unsigned mhi = (unsigned)__builtin_amdgcn_readfirstlane((int)(unsigned)(um >> 32));
    unsigned long long m = ((unsigned long long)mhi << 32) | mlo;
    // default = truth 0 with IoU 0; 2-way unrolled mask walk
    float bi = 0.f, bu = 1.f; int id = 0;
    while (m) {
      int t0 = __builtin_ctzll(m); m &= m - 1;
      float4 a0 = tb[t0]; float aa0 = ta[t0];
      if (m) {
        int t1 = __builtin_ctzll(m); m &= m - 1;
        float4 a1 = tb[t1]; float aa1 = ta[t1];
        float lx0 = fmaxf(a0.x, pr.x), ly0 = fmaxf(a0.y, pr.y);
        float rx0 = fminf(a0.z, pr.z), ry0 = fminf(a0.w, pr.w);
        float w0 = fmaxf(rx0 - lx0, 0.f), h0 = fmaxf(ry0 - ly0, 0.f);
        float in0 = w0 * h0, un0 = aa0 + ab2 - in0;
        float lx1 = fmaxf(a1.x, pr.x), ly1 = fmaxf(a1.y, pr.y);
        float rx1 = fminf(a1.z, pr.z), ry1 = fminf(a1.w, pr.w);
        float w1 = fmaxf(rx1 - lx1, 0.f), h1 = fmaxf(ry1 - ly1, 0.f);
        float in1 = w1 * h1, un1 = aa1 + ab2 - in1;
        if (in0 * bu > bi * un0) { bi = in0; bu = un0; id = t0; }
        if (in1 * bu > bi * un1) { bi = in1; bu = un1; id = t1; }
      } else {
        float lx = fmaxf(a0.x, pr.x), ly = fmaxf(a0.y, pr.y);
        float rx = fminf(a0.z, pr.z), ry = fminf(a0.w, pr.w);
        float w = fmaxf(rx - lx, 0.f), h = fmaxf(ry - ly, 0.f);
        float inter = w * h;
        float uni = aa0 + ab2 - inter;
        if (inter * bu > bi * uni) { bi = inter; bu = uni; id = t0; }
      }
    }
    if (valid) {
      float q = bi / bu;
      unsigned char posb = (q >= THRESH) ? 1 : 0;
      btpack[(long)b * PN + s] = (unsigned char)((id << 1) | posb);
    }
  }
}

// ================= K3: encode + scatter-override + partials =================
__global__ void k_encode(const float* __restrict__ loc_data,
                         const float* __restrict__ conf_data,
                         const float* __restrict__ landm_data,
                         const float* __restrict__ priors,
                         const float* __restrict__ targets,
                         const unsigned char* __restrict__ btpack,
                         const int* __restrict__ inv,
                         const unsigned long long* __restrict__ bpp,
                         float* __restrict__ lossc, unsigned char* __restrict__ posf,
                         float* __restrict__ part_l, float* __restrict__ part_lm,
                         int* __restrict__ np_part, int* __restrict__ np1_part) {
  int b = blockIdx.y;
  int p = blockIdx.x * 256 + threadIdx.x;
  int bid = b * GX + blockIdx.x;
  __shared__ float4 tgs4[ON * 15 / 4];
  __shared__ int ovr[256];
  float* tgs = (float*)tgs4;
  if (threadIdx.x < ON * 15 / 4)
    tgs4[threadIdx.x] = reinterpret_cast<const float4*>(targets + (long)b * ON * 15)[threadIdx.x];
  ovr[threadIdx.x] = -1;
  __syncthreads();
  if (threadIdx.x < ON) {
    int t = threadIdx.x;
    unsigned long long best = bpp[(long)b * ON + t];
    float q = key2f((unsigned)(best >> 32));
    int qp = (int)(~(unsigned)best);
    int s0 = blockIdx.x * 256;
    if (qp >= s0 && qp < s0 + 256) {
      int valid = (q >= 0.2f) ? 1 : 0;
      atomicMax(&ovr[qp - s0], (t << 1) | valid);
    }
  }
  __syncthreads();

  float sum_l = 0.f, sum_lm = 0.f;
  int cp = 0, cp1 = 0;
  if (p < PN) {
    unsigned pk = btpack[(long)b * PN + inv[p]];
    int t = (int)(pk >> 1);
    bool pos = (pk & 1u) != 0;
    int o = ovr[threadIdx.x];
    if (o >= 0) { t = o >> 1; if (o & 1) pos = true; }
    const float* tg = &tgs[t * 15];
    float label = tg[14];
    bool pos1 = pos && (label > 0.f);
    float4 pr = reinterpret_cast<const float4*>(priors)[p];
    if (pos) {
      float rz = 1.0f / pr.z, rw = 1.0f / pr.w;
      float m0 = tg[0], m1 = tg[1], m2 = tg[2], m3 = tg[3];
      float g0 = ((m0 + m2) * 0.5f - pr.x) * rz * 10.f;
      float g1 = ((m1 + m3) * 0.5f - pr.y) * rw * 10.f;
      float g2 = __logf((m2 - m0) * rz) * 5.f;
      float g3 = __logf((m3 - m1) * rw) * 5.f;
      const float* ld = &loc_data[((long)b * PN + p) * 4];
      sum_l = sl1(ld[0] - g0) + sl1(ld[1] - g1) + sl1(ld[2] - g2) + sl1(ld[3] - g3);
      cp = 1;
      if (pos1) {
        const float* lm = &landm_data[((long)b * PN + p) * 10];
#pragma unroll
        for (int i = 0; i < 5; i++) {
          float gx = (tg[4 + 2 * i] - pr.x) * rz * 10.f;
          float gy = (tg[5 + 2 * i] - pr.y) * rw * 10.f;
          sum_lm += sl1(lm[2 * i] - gx) + sl1(lm[2 * i + 1] - gy);
        }
        cp1 = 1;
      }
    }
    float2 c2 = reinterpret_cast<const float2*>(conf_data)[(long)b * PN + p];
    float m = fmaxf(c2.x, c2.y);
    float lse = m + __logf(__expf(c2.x - m) + __expf(c2.y - m));
    lossc[b * PN + p] = lse - (pos ? c2.y : c2.x);
    posf[b * PN + p] = pos ? 1 : 0;
  }
  for (int off = 32; off; off >>= 1) {
    sum_l += __shfl_down(sum_l, off);
    sum_lm += __shfl_down(sum_lm, off);
    cp += __shfl_down(cp, off);
    cp1 += __shfl_down(cp1, off);
  }
  __shared__ float sl4[4], slm4[4];
  __shared__ int sp4[4], sp14[4];
  int w = threadIdx.x >> 6;
  if ((threadIdx.x & 63) == 0) { sl4[w] = sum_l; slm4[w] = sum_lm; sp4[w] = cp; sp14[w] = cp1; }
  __syncthreads();
  if (threadIdx.x == 0) {
    part_l[bid] = sl4[0] + sl4[1] + sl4[2] + sl4[3];
    part_lm[bid] = slm4[0] + slm4[1] + slm4[2] + slm4[3];
    np_part[bid] = sp4[0] + sp4[1] + sp4[2] + sp4[3];
    np1_part[bid] = sp14[0] + sp14[1] + sp14[2] + sp14[3];
  }
}

// ===== K4: histogram select, vectorized float4/uint4 sweep (r5-proven) =====
__global__ void __launch_bounds__(1024) k_select(const float* __restrict__ lossc,
                                                 const unsigned char* __restrict__ posf,
                                                 const int* __restrict__ np_part,
                                                 const int* __restrict__ np1_part,
                                                 const float* __restrict__ part_l,
                                                 const float* __restrict__ part_lm,
                                                 GAcc* __restrict__ gacc,
                                                 float* __restrict__ out) {
  int b = blockIdx.x;
  int tid = threadIdx.x;
  int lane = tid & 63;
  int wv = tid >> 6;
  __shared__ unsigned hist[NBINS];
  __shared__ unsigned wtot[16];
  __shared__ float resv[MAXM];
  __shared__ int residx[MAXM];
  __shared__ int s_np, s_B, s_kp;
  __shared__ unsigned s_mc;
  const float* row = &lossc[(long)b * PN];
  const unsigned char* prow = &posf[(long)b * PN];

  if (tid == 0) s_np = 0;
  for (int i = tid; i < NBINS; i += 1024) hist[i] = 0;
  __syncthreads();
  if (tid < GX) atomicAdd(&s_np, np_part[b * GX + tid]);

  const float4* rf4 = reinterpret_cast<const float4*>(row);
  const uint4* pw4 = reinterpret_cast<const uint4*>(prow);
  bool hasTail = tid < TAILT;
  float vm[16];
  float vt[4];
  {
    float4 L0 = rf4[tid * 4], L1 = rf4[tid * 4 + 1], L2 = rf4[tid * 4 + 2], L3 = rf4[tid * 4 + 3];
    vm[0] = L0.x; vm[1] = L0.y; vm[2] = L0.z; vm[3] = L0.w;
    vm[4] = L1.x; vm[5] = L1.y; vm[6] = L1.z; vm[7] = L1.w;
    vm[8] = L2.x; vm[9] = L2.y; vm[10] = L2.z; vm[11] = L2.w;
    vm[12] = L3.x; vm[13] = L3.y; vm[14] = L3.z; vm[15] = L3.w;
  }
  unsigned pmask = 0;
  {
    uint4 W = pw4[tid];
    unsigned w0 = W.x, w1 = W.y, w2 = W.z, w3 = W.w;
#pragma unroll
    for (int j = 0; j < 4; j++) {
      pmask |= ((w0 >> (8 * j)) & 1u) << j;
      pmask |= ((w1 >> (8 * j)) & 1u) << (4 + j);
      pmask |= ((w2 >> (8 * j)) & 1u) << (8 + j);
      pmask |= ((w3 >> (8 * j)) & 1u) << (12 + j);
    }
  }
  unsigned tmask = 0;
  if (hasTail) {
    float4 Lt = rf4[4096 + tid];
    vt[0] = Lt.x; vt[1] = Lt.y; vt[2] = Lt.z; vt[3] = Lt.w;
    unsigned Wt = reinterpret_cast<const unsigned*>(prow)[4096 + tid];
#pragma unroll
    for (int j = 0; j < 4; j++) tmask |= ((Wt >> (8 * j)) & 1u) << j;
  } else {
    vt[0] = vt[1] = vt[2] = vt[3] = -1.f;
  }
  int bm[16], bt4[4];
#pragma unroll
  for (int j = 0; j < 16; j++) {
    int q = (int)(vm[j] * 256.0f);
    bm[j] = q < 0 ? 0 : (q > NBINS - 1 ? NBINS - 1 : q);
  }
#pragma unroll
  for (int j = 0; j < 4; j++) {
    int q = (int)(vt[j] * 256.0f);
    bt4[j] = q < 0 ? 0 : (q > NBINS - 1 ? NBINS - 1 : q);
  }
  __syncthreads();
  int np = s_np;
  int k = NEGPOS * np;
  if (k > PN - 1) k = PN - 1;
  bool haveNeg = (k > 0);

  int B = NBINS, kp = 0, m = 0;
  bool allB = false, fallback = false;
  if (haveNeg) {
#pragma unroll
    for (int j = 0; j < 16; j++) atomicAdd(&hist[bm[j]], 1u);
    if (hasTail) {
#pragma unroll
      for (int j = 0; j < 4; j++) atomicAdd(&hist[bt4[j]], 1u);
    }
    __syncthreads();
    int t4 = tid * 4;
    unsigned h0 = hist[t4], h1 = hist[t4 + 1], h2 = hist[t4 + 2], h3 = hist[t4 + 3];
    unsigned th = h0 + h1 + h2 + h3;
    unsigned v = th;
#pragma unroll
    for (int off = 1; off < 64; off <<= 1) {
      unsigned tv = (unsigned)__shfl_down((int)v, off);
      if (lane + off < 64) v += tv;
    }
    if (lane == 0) wtot[wv] = v;
    __syncthreads();
    unsigned add = 0;
    for (int w2 = wv + 1; w2 < 16; w2++) add += wtot[w2];
    unsigned S_t = v + add;
    unsigned S_next = S_t - th;
    if (S_t >= (unsigned)k && S_next < (unsigned)k) {
      unsigned run = S_next; int Bl; unsigned kpl;
      if (run + h3 >= (unsigned)k) { Bl = t4 + 3; kpl = k - run; }
      else { run += h3;
        if (run + h2 >= (unsigned)k) { Bl = t4 + 2; kpl = k - run; }
        else { run += h2;
          if (run + h1 >= (unsigned)k) { Bl = t4 + 1; kpl = k - run; }
          else { run += h1; Bl = t4; kpl = k - run; } } }
      s_B = Bl; s_kp = (int)kpl;
    }
    __syncthreads();
    B = s_B; kp = s_kp; m = (int)hist[B];
    allB = (kp == m);
    fallback = (!allB && m > MAXM);
  }

  float acc = 0.f;
  if (haveNeg && !allB && !fallback) {
    if (tid == 0) s_mc = 0;
    __syncthreads();
#pragma unroll
    for (int j = 0; j < 16; j++) {
      if (bm[j] == B) {
        unsigned slot = atomicAdd(&s_mc, 1u);
        resv[slot] = vm[j];
        residx[slot] = (tid * 16 + j) | (((pmask >> j) & 1u) ? 0x40000000 : 0);
      }
    }
    if (hasTail) {
#pragma unroll
      for (int j = 0; j < 4; j++) {
        if (bt4[j] == B) {
          unsigned slot = atomicAdd(&s_mc, 1u);
          resv[slot] = vt[j];
          residx[slot] = (16384 + tid * 4 + j) | (((tmask >> j) & 1u) ? 0x40000000 : 0);
        }
      }
    }
    __syncthreads();
    for (int i = tid; i < m; i += 1024) {
      float vi = resv[i];
      int pk = residx[i];
      int ii = pk & 0x3FFFFFFF;
      bool posi = (pk & 0x40000000) != 0;
      int rank = 0;
      for (int j = 0; j < m; j++) {
        float vj = resv[j];
        int ij = residx[j] & 0x3FFFFFFF;
        rank += (vj > vi || (vj == vi && ij < ii)) ? 1 : 0;
      }
      if (rank < kp && !posi) acc += vi;
    }
  }

  unsigned T = 0, R = 0, C = 0;
  if (fallback) {
    __shared__ unsigned s_lo, s_hi, fcnt[16];
    if (tid == 0) { s_lo = 0u; s_hi = 0xFFFFFFFFu; }
    __syncthreads();
    for (int it = 0; it < 32; it++) {
      unsigned lo = s_lo, hi = s_hi;
      unsigned mid = lo + ((hi - lo) >> 1) + ((hi - lo) & 1u);
      unsigned c = 0;
#pragma unroll
      for (int j = 0; j < 16; j++) c += (f2key(vm[j]) >= mid) ? 1u : 0u;
      if (hasTail) {
#pragma unroll
        for (int j = 0; j < 4; j++) c += (f2key(vt[j]) >= mid) ? 1u : 0u;
      }
#pragma unroll
      for (int o = 32; o; o >>= 1) c += (unsigned)__shfl_down((int)c, o);
      if (lane == 0) fcnt[wv] = c;
      __syncthreads();
      if (tid == 0) {
        unsigned tot = 0;
        for (int i = 0; i < 16; i++) tot += fcnt[i];
        if (tot >= (unsigned)k) s_lo = mid; else s_hi = mid - 1;
      }
      __syncthreads();
      if (s_lo >= s_hi) break;
    }
    T = s_lo;
    unsigned cg = 0, ce = 0;
#pragma unroll
    for (int j = 0; j < 16; j++) {
      unsigned key = f2key(vm[j]);
      cg += (key > T) ? 1u : 0u;
      ce += (key == T) ? 1u : 0u;
    }
    if (hasTail) {
#pragma unroll
      for (int j = 0; j < 4; j++) {
        unsigned key = f2key(vt[j]);
        cg += (key > T) ? 1u : 0u;
        ce += (key == T) ? 1u : 0u;
      }
    }
#pragma unroll
    for (int o = 32; o; o >>= 1) {
      cg += (unsigned)__shfl_down((int)cg, o);
      ce += (unsigned)__shfl_down((int)ce, o);
    }
    if (lane == 0) { fcnt[wv] = cg; wtot[wv] = ce; }
    __syncthreads();
    if (tid == 0) {
      unsigned tg2 = 0, te = 0;
      for (int i = 0; i < 16; i++) { tg2 += fcnt[i]; te += wtot[i]; }
      fcnt[0] = tg2; wtot[0] = te;
    }
    __syncthreads();
    C = wtot[0];
    R = (unsigned)k - fcnt[0];
    if (C != R && tid < 64) {
      unsigned running = 0;
      for (int base2 = 0; base2 < PN; base2 += 64) {
        int p = base2 + tid;
        bool tie = false, pos = false;
        float v2 = 0.f;
        if (p < PN) { v2 = row[p]; tie = (f2key(v2) == T); pos = prow[p] != 0; }
        unsigned long long mm = __ballot(tie);
        if (tie) {
          unsigned rank = running + (unsigned)__popcll(mm & ((1ull << tid) - 1));
          if (rank < R && !pos) acc += v2;
        }
        running += (unsigned)__popcll(mm);
      }
    }
  }

  unsigned ptc = 0;
#pragma unroll
  for (int j = 0; j < 16; j++) {
    float v2 = vm[j];
    bool pos = (pmask >> j) & 1u;
    if (pos) acc += v2;
    else if (haveNeg) {
      if (!fallback) {
        if (bm[j] > B || (bm[j] == B && allB)) acc += v2;
      } else {
        if (f2key(v2) > T) acc += v2;
      }
    }
    if (fallback && pos && f2key(v2) == T) ptc++;
  }
  if (hasTail) {
#pragma unroll
    for (int j = 0; j < 4; j++) {
      float v2 = vt[j];
      bool pos = (tmask >> j) & 1u;
      if (pos) acc += v2;
      else if (haveNeg) {
        if (!fallback) {
          if (bt4[j] > B || (bt4[j] == B && allB)) acc += v2;
        } else {
          if (f2key(v2) > T) acc += v2;
        }
      }
      if (fallback && pos && f2key(v2) == T) ptc++;
    }
  }
  for (int o = 32; o; o >>= 1) {
    acc += __shfl_down(acc, o);
    ptc += __shfl_down(ptc, o);
  }
  __shared__ float wsum[16];
  __shared__ unsigned wpt[16];
  if (lane == 0) { wsum[wv] = acc; wpt[wv] = ptc; }
  __syncthreads();

  __shared__ float s_rsl, s_rslm;
  __shared__ int s_rnp1;
  if (tid == 0) { s_rsl = 0.f; s_rslm = 0.f; s_rnp1 = 0; }
  __syncthreads();
  if (tid < GX) {
    atomicAdd(&s_rsl, part_l[b * GX + tid]);
    atomicAdd(&s_rslm, part_lm[b * GX + tid]);
    atomicAdd(&s_rnp1, np1_part[b * GX + tid]);
  }
  __syncthreads();

  if (tid == 0) {
    float tot = 0.f; unsigned pt = 0;
    for (int i = 0; i < 16; i++) { tot += wsum[i]; pt += wpt[i]; }
    if (fallback && C == R) tot += (float)(C - pt) * key2f(T);
    atomicAdd(&gacc->sc, tot);
    atomicAdd(&gacc->sl, s_rsl);
    atomicAdd(&gacc->slm, s_rslm);
    atomicAdd(&gacc->np, np);
    atomicAdd(&gacc->np1, s_rnp1);
  }
  __threadfence();
  __shared__ int lastF;
  if (tid == 0) lastF = (atomicAdd(&gacc->ticket, 1u) == (unsigned)(BN - 1)) ? 1 : 0;
  __syncthreads();
  if (lastF && tid == 0) {
    __threadfence();
    float sl = atomicAdd(&gacc->sl, 0.f);
    float slm = atomicAdd(&gacc->slm, 0.f);
    float sc = atomicAdd(&gacc->sc, 0.f);
    int tnp = atomicAdd(&gacc->np, 0);
    int tnp1 = atomicAdd(&gacc->np1, 0);
    float N = fmaxf((float)tnp, 1.f);
    float N1 = fmaxf((float)tnp1, 1.f);
    out[0] = sl / N;
    out[1] = sc / N;
    out[2] = slm / N1;
  }
}

extern "C" void kernel_launch(void* const* d_in, const int* in_sizes, int n_in,
                              void* d_out, int out_size, void* d_ws, size_t ws_size,
                              hipStream_t stream) {
  const float* loc_data = (const float*)d_in[0];
  const float* conf_data = (const float*)d_in[1];
  const float* landm_data = (const float*)d_in[2];
  const float* priors = (const float*)d_in[3];
  const float* targets = (const float*)d_in[4];
  float* out = (float*)d_out;

  char* ws = (char*)d_ws;
  size_t off = 0;
  float* lossc = (float*)(ws + off); off += (size_t)BN * PN * 4;              // 4.30 MB
  unsigned char* btpack = (unsigned char*)(ws + off); off += (size_t)BN * PN; // 1.07 MB
  unsigned char* posf = (unsigned char*)(ws + off); off += (size_t)BN * PN;   // 1.07 MB
  off = (off + 15) & ~(size_t)15;
  unsigned long long* bpp = (unsigned long long*)(ws + off); off += (size_t)BN * ON * 8;
  float* part_l = (float*)(ws + off); off += NBLK * 4;
  float* part_lm = (float*)(ws + off); off += NBLK * 4;
  int* np_part = (int*)(ws + off); off += NBLK * 4;
  int* np1_part = (int*)(ws + off); off += NBLK * 4;
  float4* sbox = (float4*)(ws + off); off += (size_t)PN * 16;
  int* sorig = (int*)(ws + off); off += (size_t)PN * 4;
  int* scell = (int*)(ws + off); off += (size_t)PN * 4;
  int* inv = (int*)(ws + off); off += (size_t)PN * 4;
  unsigned char* pcell = (unsigned char*)(ws + off); off += (size_t)PN;
  off = (off + 15) & ~(size_t)15;
  int* cellOff = (int*)(ws + off); off += 260 * 4;
  unsigned long long* tmask = (unsigned long long*)(ws + off); off += (size_t)BN * NCELL * 8;
  off = (off + 15) & ~(size_t)15;
  unsigned* bhist = (unsigned*)(ws + off); off += (size_t)NCB * NCELL * 4;    // 67.6 KB
  float* gmaxblk = (float*)(ws + off); off += (size_t)NCB * 2 * 4;
  unsigned* gmax = (unsigned*)(ws + off); off += 16;
  GAcc* gacc = (GAcc*)(ws + off); off += sizeof(GAcc);
  // total ~7.3 MB

  k_count<<<NCB, 256, 0, stream>>>(priors, pcell, bhist, gmaxblk, gacc);
  k_scatter<<<NCB + BN, 256, 0, stream>>>(priors, targets, pcell, bhist, gmaxblk, gmax,
                                          sbox, sorig, scell, inv, cellOff, tmask);
  k_pair<<<NBP + NBTT, 256, 0, stream>>>(targets, sbox, sorig, scell, cellOff, gmax,
                                         tmask, btpack, bpp);
  dim3 gbp(GX, BN);
  k_encode<<<gbp, 256, 0, stream>>>(loc_data, conf_data, landm_data, priors, targets,
                                    btpack, inv, bpp, lossc, posf,
                                    part_l, part_lm, np_part, np1_part);
  k_select<<<BN, 1024, 0, stream>>>(lossc, posf, np_part, np1_part, part_l, part_lm,
                                    gacc, out);
}

// Round 13
// 185.635 us; speedup vs baseline: 1.4886x; 1.0101x over previous
//
#include <hip/hip_runtime.h>
#include <math.h>

#define BN 64
#define PN 16800
#define ON 64
#define THRESH 0.35f
#define NEGPOS 7
#define GX 66                  // encode/bt slabs per row (66*256 >= 16800)
#define NBLK (BN * GX)         // 4224 partial slots
#define NBP 1024               // bp blocks (64 b * 16 blocks of 4 truths)
#define NBTT (BN * GX)         // 4224 bt blocks
#define NCELL 256              // 16x16 spatial cells
#define NCB 66                 // count/scatter blocks (66*256 >= 16800)
#define EPSW 0.0009765625f     // 1/1024: absorbs float rounding in window math
#define NBINS 4096
#define MAXM 4096
#define TAILT 104              // threads with tail work in select (416/4)

struct GAcc {
  unsigned ticket;
  float sl, slm, sc;
  int np, np1;
  unsigned pad0, pad1;
};

__device__ __forceinline__ unsigned f2key(float f) {
  unsigned u = __float_as_uint(f);
  return (u & 0x80000000u) ? ~u : (u | 0x80000000u);
}
__device__ __forceinline__ float key2f(unsigned k) {
  unsigned u = (k & 0x80000000u) ? (k & 0x7FFFFFFFu) : ~k;
  return __uint_as_float(u);
}
__device__ __forceinline__ float sl1(float d) {
  float a = fabsf(d);
  return (a < 1.f) ? 0.5f * a * a : a - 0.5f;
}

// ====== K0: wide count — per-block histograms (no memset, no global atomics) ======
__global__ void k_count(const float* __restrict__ priors,
                        unsigned char* __restrict__ pcell,
                        unsigned* __restrict__ bhist,
                        float* __restrict__ gmaxblk,
                        GAcc* __restrict__ gacc) {
  __shared__ unsigned lcnt[NCELL];
  __shared__ float swm[4], swh[4];
  int tid = threadIdx.x;
  int bid = blockIdx.x;
  lcnt[tid] = 0;
  if (bid == 0 && tid < 8) ((unsigned*)gacc)[tid] = 0;
  __syncthreads();
  int p = bid * 256 + tid;
  float mw = 0.f, mh = 0.f;
  if (p < PN) {
    float4 pr = reinterpret_cast<const float4*>(priors)[p];
    int cx = (int)(pr.x * 16.f); cx = cx < 0 ? 0 : (cx > 15 ? 15 : cx);
    int cy = (int)(pr.y * 16.f); cy = cy < 0 ? 0 : (cy > 15 ? 15 : cy);
    int cell = cy * 16 + cx;
    pcell[p] = (unsigned char)cell;
    atomicAdd(&lcnt[cell], 1u);
    mw = pr.z * 0.5f;
    mh = pr.w * 0.5f;
  }
#pragma unroll
  for (int off = 32; off; off >>= 1) {
    mw = fmaxf(mw, __shfl_xor(mw, off));
    mh = fmaxf(mh, __shfl_xor(mh, off));
  }
  if ((tid & 63) == 0) { swm[tid >> 6] = mw; swh[tid >> 6] = mh; }
  __syncthreads();
  if (tid == 0) {
    gmaxblk[bid * 2] = fmaxf(fmaxf(swm[0], swm[1]), fmaxf(swm[2], swm[3]));
    gmaxblk[bid * 2 + 1] = fmaxf(fmaxf(swh[0], swh[1]), fmaxf(swh[2], swh[3]));
  }
  bhist[bid * NCELL + tid] = lcnt[tid];
}

// ====== K1: wide scatter (blocks 0..65) + per-(b,cell) truth masks (66..129) ======
__global__ void k_scatter(const float* __restrict__ priors,
                          const float* __restrict__ targets,
                          const unsigned char* __restrict__ pcell,
                          const unsigned* __restrict__ bhist,
                          const float* __restrict__ gmaxblk,
                          unsigned* __restrict__ gmax,
                          float4* __restrict__ sbox,
                          int* __restrict__ sorig,
                          int* __restrict__ scell,
                          int* __restrict__ inv,
                          int* __restrict__ cellOff,
                          unsigned long long* __restrict__ tmask) {
  int bid = blockIdx.x;
  int tid = threadIdx.x;
  if (bid < NCB) {
    __shared__ unsigned tmp[NCELL];
    __shared__ unsigned sbase[NCELL];
    __shared__ unsigned lcnt[NCELL];
    // sum per-block histograms; this block's base within cell = earlier blocks
    unsigned tot = 0, mybase = 0;
#pragma unroll 4
    for (int b2 = 0; b2 < NCB; b2++) {
      unsigned h = bhist[b2 * NCELL + tid];
      if (b2 < bid) mybase += h;
      tot += h;
    }
    tmp[tid] = tot;
    lcnt[tid] = 0;
    __syncthreads();
    // inclusive ladder scan over 256 bins (redundant per block; counts final)
    for (int off = 1; off < NCELL; off <<= 1) {
      unsigned v = (tid >= off) ? tmp[tid - off] : 0u;
      __syncthreads();
      tmp[tid] += v;
      __syncthreads();
    }
    unsigned excl = tmp[tid] - tot;
    sbase[tid] = excl + mybase;
    if (bid == 0) {
      cellOff[tid] = (int)excl;
      if (tid == 0) {
        cellOff[NCELL] = PN;
        float MW = 0.f, MH = 0.f;
        for (int i = 0; i < NCB; i++) {
          MW = fmaxf(MW, gmaxblk[2 * i]);
          MH = fmaxf(MH, gmaxblk[2 * i + 1]);
        }
        gmax[0] = __float_as_uint(MW);   // consumed by k_pair (next launch)
        gmax[1] = __float_as_uint(MH);
      }
    }
    __syncthreads();
    int p = bid * 256 + tid;
    if (p < PN) {
      int cell = pcell[p];
      unsigned lrank = atomicAdd(&lcnt[cell], 1u);
      int slot = (int)(sbase[cell] + lrank);
      float4 pr = reinterpret_cast<const float4*>(priors)[p];
      float px1 = pr.x - pr.z * 0.5f, py1 = pr.y - pr.w * 0.5f;
      float px2 = pr.x + pr.z * 0.5f, py2 = pr.y + pr.w * 0.5f;
      sbox[slot] = make_float4(px1, py1, px2, py2);
      sorig[slot] = p;
      scell[slot] = cell;
      inv[p] = slot;
    }
  } else {
    // ---- masks role: b = bid - NCB; thread = cell (r5-proven window) ----
    int b = bid - NCB;
    __shared__ float4 tb[ON];
    if (tid < ON) {
      const float* tg = &targets[((long)b * ON + tid) * 15];
      tb[tid] = make_float4(tg[0], tg[1], tg[2], tg[3]);
    }
    __syncthreads();
    float MW = 0.f, MH = 0.f;
    for (int i = 0; i < NCB; i++) {
      MW = fmaxf(MW, gmaxblk[2 * i]);
      MH = fmaxf(MH, gmaxblk[2 * i + 1]);
    }
    int cx = tid & 15, cy = tid >> 4;
    // tight window: 1 cell + max prior half-extent + ulp guard (EPSW >> ulp)
    float x0 = (float)cx * 0.0625f - MW - EPSW, x1 = (float)(cx + 1) * 0.0625f + MW + EPSW;
    float y0 = (float)cy * 0.0625f - MH - EPSW, y1 = (float)(cy + 1) * 0.0625f + MH + EPSW;
    unsigned long long m = 0ull;
    for (int t = 0; t < ON; t++) {
      float4 a = tb[t];
      if (x0 < a.z && x1 > a.x && y0 < a.w && y1 > a.y) m |= (1ull << t);
    }
    tmask[b * NCELL + tid] = m;
  }
}

// ====== K2: pruned best-prior (per truth) + pruned best-truth (per prior) ======
__global__ void k_pair(const float* __restrict__ targets,
                       const float4* __restrict__ sbox,
                       const int* __restrict__ sorig,
                       const int* __restrict__ scell,
                       const int* __restrict__ cellOff,
                       const unsigned* __restrict__ gmax,
                       const unsigned long long* __restrict__ tmask,
                       unsigned char* __restrict__ btpack,
                       unsigned long long* __restrict__ bpp) {
  int bid = blockIdx.x;
  int tid = threadIdx.x;

  if (bid < NBP) {
    // ---- best-prior role: one wave per (b, truth), scan candidate cell rows ----
    int lane = tid & 63, wv = tid >> 6;
    int b = bid >> 4;
    int t = ((bid & 15) << 2) + wv;
    const float* tg = &targets[((long)b * ON + t) * 15];
    float ax1 = tg[0], ay1 = tg[1], ax2 = tg[2], ay2 = tg[3];
    float aa = (ax2 - ax1) * (ay2 - ay1);
    float MW = __uint_as_float(gmax[0]), MH = __uint_as_float(gmax[1]);
    int xlo = (int)floorf((ax1 - MW - EPSW) * 16.f); xlo = xlo < 0 ? 0 : (xlo > 15 ? 15 : xlo);
    int xhi = (int)floorf((ax2 + MW + EPSW) * 16.f); xhi = xhi < 0 ? 0 : (xhi > 15 ? 15 : xhi);
    int ylo = (int)floorf((ay1 - MH - EPSW) * 16.f); ylo = ylo < 0 ? 0 : (ylo > 15 ? 15 : ylo);
    int yhi = (int)floorf((ay2 + MH + EPSW) * 16.f); yhi = yhi < 0 ? 0 : (yhi > 15 ? 15 : yhi);
    // default = prior 0 with IoU 0 (matches reference argmax over all-zero overlaps)
    float bi = 0.f, bu = 1.f; int bp = 0;
    for (int cy = ylo; cy <= yhi; cy++) {
      int s0 = cellOff[cy * 16 + xlo];
      int s1 = cellOff[cy * 16 + xhi + 1];
      for (int s = s0 + lane; s < s1; s += 64) {
        float4 pr = sbox[s];
        int op = sorig[s];
        float ab2 = (pr.z - pr.x) * (pr.w - pr.y);
        float lx = fmaxf(ax1, pr.x), ly = fmaxf(ay1, pr.y);
        float rx = fminf(ax2, pr.z), ry = fminf(ay2, pr.w);
        float w = fmaxf(rx - lx, 0.f), h = fmaxf(ry - ly, 0.f);
        float inter = w * h;
        float uni = aa + ab2 - inter;
        float A = inter * bu, C = bi * uni;
        if (A > C || (A == C && op < bp)) { bi = inter; bu = uni; bp = op; }
      }
    }
#pragma unroll
    for (int off = 1; off < 64; off <<= 1) {
      float oi = __shfl_xor(bi, off), ou = __shfl_xor(bu, off);
      int op = __shfl_xor(bp, off);
      float A = oi * bu, C = bi * ou;
      if (A > C || (A == C && op < bp)) { bi = oi; bu = ou; bp = op; }
    }
    if (lane == 0) {
      float q = bi / bu;
      bpp[(long)b * ON + t] = ((unsigned long long)f2key(q) << 32) | (unsigned)(~bp);
    }
  } else {
    // ---- best-truth role: one thread per sorted prior, wave-union truth mask
    // (wave-uniform walk => every LDS read is a broadcast, no divergence) ----
    int id2 = bid - NBP;
    int b = id2 / GX;
    int slab = id2 - b * GX;
    int s = slab * 256 + tid;
    bool valid = s < PN;
    int sc = valid ? s : PN - 1;
    __shared__ float4 tb[ON];
    __shared__ float ta[ON];
    if (tid < ON) {
      const float* tg = &targets[((long)b * ON + tid) * 15];
      float4 bx = make_float4(tg[0], tg[1], tg[2], tg[3]);
      tb[tid] = bx;
      ta[tid] = (bx.z - bx.x) * (bx.w - bx.y);
    }
    __syncthreads();
    float4 pr = sbox[sc];
    float ab2 = (pr.z - pr.x) * (pr.w - pr.y);
    unsigned long long um = valid ? tmask[b * NCELL + scell[sc]] : 0ull;
#pragma unroll
    for (int off = 1; off < 64; off <<= 1) um |= __shfl_xor(um, off);
    unsigned mlo = (unsigned)__builtin_amdgcn_readfirstlane((int)(unsigned)um);
    unsigned mhi = (unsigned)__builtin_amdgcn_readfirstlane((int)(unsigned)(um >> 32));
    unsigned long long m = ((unsigned long long)mhi << 32) | mlo;
    // default = truth 0 with IoU 0; 2-way unrolled mask walk
    float bi = 0.f, bu = 1.f; int id = 0;
    while (m) {
      int t0 = __builtin_ctzll(m); m &= m - 1;
      float4 a0 = tb[t0]; float aa0 = ta[t0];
      if (m) {
        int t1 = __builtin_ctzll(m); m &= m - 1;
        float4 a1 = tb[t1]; float aa1 = ta[t1];
        float lx0 = fmaxf(a0.x, pr.x), ly0 = fmaxf(a0.y, pr.y);
        float rx0 = fminf(a0.z, pr.z), ry0 = fminf(a0.w, pr.w);
        float w0 = fmaxf(rx0 - lx0, 0.f), h0 = fmaxf(ry0 - ly0, 0.f);
        float in0 = w0 * h0, un0 = aa0 + ab2 - in0;
        float lx1 = fmaxf(a1.x, pr.x), ly1 = fmaxf(a1.y, pr.y);
        float rx1 = fminf(a1.z, pr.z), ry1 = fminf(a1.w, pr.w);
        float w1 = fmaxf(rx1 - lx1, 0.f), h1 = fmaxf(ry1 - ly1, 0.f);
        float in1 = w1 * h1, un1 = aa1 + ab2 - in1;
        if (in0 * bu > bi * un0) { bi = in0; bu = un0; id = t0; }
        if (in1 * bu > bi * un1) { bi = in1; bu = un1; id = t1; }
      } else {
        float lx = fmaxf(a0.x, pr.x), ly = fmaxf(a0.y, pr.y);
        float rx = fminf(a0.z, pr.z), ry = fminf(a0.w, pr.w);
        float w = fmaxf(rx - lx, 0.f), h = fmaxf(ry - ly, 0.f);
        float inter = w * h;
        float uni = aa0 + ab2 - inter;
        if (inter * bu > bi * uni) { bi = inter; bu = uni; id = t0; }
      }
    }
    if (valid) {
      float q = bi / bu;
      unsigned char posb = (q >= THRESH) ? 1 : 0;
      btpack[(long)b * PN + s] = (unsigned char)((id << 1) | posb);
    }
  }
}

// ================= K3: encode + scatter-override + partials =================
__global__ void k_encode(const float* __restrict__ loc_data,
                         const float* __restrict__ conf_data,
                         const float* __restrict__ landm_data,
                         const float* __restrict__ priors,
                         const float* __restrict__ targets,
                         const unsigned char* __restrict__ btpack,
                         const int* __restrict__ inv,
                         const unsigned long long* __restrict__ bpp,
                         float* __restrict__ lossc, unsigned char* __restrict__ posf,
                         float* __restrict__ part_l, float* __restrict__ part_lm,
                         int* __restrict__ np_part, int* __restrict__ np1_part) {
  int b = blockIdx.y;
  int p = blockIdx.x * 256 + threadIdx.x;
  int bid = b * GX + blockIdx.x;
  __shared__ float4 tgs4[ON * 15 / 4];
  __shared__ int ovr[256];
  float* tgs = (float*)tgs4;
  if (threadIdx.x < ON * 15 / 4)
    tgs4[threadIdx.x] = reinterpret_cast<const float4*>(targets + (long)b * ON * 15)[threadIdx.x];
  ovr[threadIdx.x] = -1;
  __syncthreads();
  if (threadIdx.x < ON) {
    int t = threadIdx.x;
    unsigned long long best = bpp[(long)b * ON + t];
    float q = key2f((unsigned)(best >> 32));
    int qp = (int)(~(unsigned)best);
    int s0 = blockIdx.x * 256;
    if (qp >= s0 && qp < s0 + 256) {
      int valid = (q >= 0.2f) ? 1 : 0;
      atomicMax(&ovr[qp - s0], (t << 1) | valid);
    }
  }
  __syncthreads();

  float sum_l = 0.f, sum_lm = 0.f;
  int cp = 0, cp1 = 0;
  if (p < PN) {
    unsigned pk = btpack[(long)b * PN + inv[p]];
    int t = (int)(pk >> 1);
    bool pos = (pk & 1u) != 0;
    int o = ovr[threadIdx.x];
    if (o >= 0) { t = o >> 1; if (o & 1) pos = true; }
    const float* tg = &tgs[t * 15];
    float label = tg[14];
    bool pos1 = pos && (label > 0.f);
    float4 pr = reinterpret_cast<const float4*>(priors)[p];
    if (pos) {
      float rz = 1.0f / pr.z, rw = 1.0f / pr.w;
      float m0 = tg[0], m1 = tg[1], m2 = tg[2], m3 = tg[3];
      float g0 = ((m0 + m2) * 0.5f - pr.x) * rz * 10.f;
      float g1 = ((m1 + m3) * 0.5f - pr.y) * rw * 10.f;
      float g2 = __logf((m2 - m0) * rz) * 5.f;
      float g3 = __logf((m3 - m1) * rw) * 5.f;
      // vectorized: loc_data row is 16B-aligned ((b*PN+p)*4 floats)
      float4 ld = reinterpret_cast<const float4*>(loc_data)[(long)b * PN + p];
      sum_l = sl1(ld.x - g0) + sl1(ld.y - g1) + sl1(ld.z - g2) + sl1(ld.w - g3);
      cp = 1;
      if (pos1) {
        // vectorized: landm row offset (b*PN+p)*40 B is 8B-aligned -> float2 x5
        const float2* lm2 = reinterpret_cast<const float2*>(&landm_data[((long)b * PN + p) * 10]);
#pragma unroll
        for (int i = 0; i < 5; i++) {
          float2 lm = lm2[i];
          float gx = (tg[4 + 2 * i] - pr.x) * rz * 10.f;
          float gy = (tg[5 + 2 * i] - pr.y) * rw * 10.f;
          sum_lm += sl1(lm.x - gx) + sl1(lm.y - gy);
        }
        cp1 = 1;
      }
    }
    float2 c2 = reinterpret_cast<const float2*>(conf_data)[(long)b * PN + p];
    float m = fmaxf(c2.x, c2.y);
    float lse = m + __logf(__expf(c2.x - m) + __expf(c2.y - m));
    lossc[b * PN + p] = lse - (pos ? c2.y : c2.x);
    posf[b * PN + p] = pos ? 1 : 0;
  }
  for (int off = 32; off; off >>= 1) {
    sum_l += __shfl_down(sum_l, off);
    sum_lm += __shfl_down(sum_lm, off);
    cp += __shfl_down(cp, off);
    cp1 += __shfl_down(cp1, off);
  }
  __shared__ float sl4[4], slm4[4];
  __shared__ int sp4[4], sp14[4];
  int w = threadIdx.x >> 6;
  if ((threadIdx.x & 63) == 0) { sl4[w] = sum_l; slm4[w] = sum_lm; sp4[w] = cp; sp14[w] = cp1; }
  __syncthreads();
  if (threadIdx.x == 0) {
    part_l[bid] = sl4[0] + sl4[1] + sl4[2] + sl4[3];
    part_lm[bid] = slm4[0] + slm4[1] + slm4[2] + slm4[3];
    np_part[bid] = sp4[0] + sp4[1] + sp4[2] + sp4[3];
    np1_part[bid] = sp14[0] + sp14[1] + sp14[2] + sp14[3];
  }
}

// ===== K4: histogram select (r5-proven logic) with coalesced interleaved loads:
// element(c,f) = 4*(c*1024+tid)+f — 16B lane stride, true global indices kept =====
__global__ void __launch_bounds__(1024) k_select(const float* __restrict__ lossc,
                                                 const unsigned char* __restrict__ posf,
                                                 const int* __restrict__ np_part,
                                                 const int* __restrict__ np1_part,
                                                 const float* __restrict__ part_l,
                                                 const float* __restrict__ part_lm,
                                                 GAcc* __restrict__ gacc,
                                                 float* __restrict__ out) {
  int b = blockIdx.x;
  int tid = threadIdx.x;
  int lane = tid & 63;
  int wv = tid >> 6;
  __shared__ unsigned hist[NBINS];
  __shared__ unsigned wtot[16];
  __shared__ float resv[MAXM];
  __shared__ int residx[MAXM];
  __shared__ int s_np, s_B, s_kp;
  __shared__ unsigned s_mc;
  const float* row = &lossc[(long)b * PN];
  const unsigned char* prow = &posf[(long)b * PN];

  if (tid == 0) s_np = 0;
  for (int i = tid; i < NBINS; i += 1024) hist[i] = 0;
  __syncthreads();
  if (tid < GX) atomicAdd(&s_np, np_part[b * GX + tid]);

  const float4* rf4 = reinterpret_cast<const float4*>(row);
  const unsigned* pw = reinterpret_cast<const unsigned*>(prow);
  bool hasTail = tid < TAILT;
  float vm[16];
  float vt[4];
  unsigned pmask = 0;
  {
#pragma unroll
    for (int c = 0; c < 4; c++) {
      float4 L = rf4[c * 1024 + tid];            // coalesced: 16B lane stride
      vm[c * 4 + 0] = L.x; vm[c * 4 + 1] = L.y;
      vm[c * 4 + 2] = L.z; vm[c * 4 + 3] = L.w;
      unsigned W = pw[c * 1024 + tid];           // 4 posf bytes for these elems
#pragma unroll
      for (int f = 0; f < 4; f++) pmask |= ((W >> (8 * f)) & 1u) << (c * 4 + f);
    }
  }
  unsigned tmask = 0;
  if (hasTail) {
    float4 Lt = rf4[4096 + tid];
    vt[0] = Lt.x; vt[1] = Lt.y; vt[2] = Lt.z; vt[3] = Lt.w;
    unsigned Wt = pw[4096 + tid];
#pragma unroll
    for (int j = 0; j < 4; j++) tmask |= ((Wt >> (8 * j)) & 1u) << j;
  } else {
    vt[0] = vt[1] = vt[2] = vt[3] = -1.f;
  }
  int bm[16], bt4[4];
#pragma unroll
  for (int j = 0; j < 16; j++) {
    int q = (int)(vm[j] * 256.0f);
    bm[j] = q < 0 ? 0 : (q > NBINS - 1 ? NBINS - 1 : q);
  }
#pragma unroll
  for (int j = 0; j < 4; j++) {
    int q = (int)(vt[j] * 256.0f);
    bt4[j] = q < 0 ? 0 : (q > NBINS - 1 ? NBINS - 1 : q);
  }
  __syncthreads();
  int np = s_np;
  int k = NEGPOS * np;
  if (k > PN - 1) k = PN - 1;
  bool haveNeg = (k > 0);

  int B = NBINS, kp = 0, m = 0;
  bool allB = false, fallback = false;
  if (haveNeg) {
#pragma unroll
    for (int j = 0; j < 16; j++) atomicAdd(&hist[bm[j]], 1u);
    if (hasTail) {
#pragma unroll
      for (int j = 0; j < 4; j++) atomicAdd(&hist[bt4[j]], 1u);
    }
    __syncthreads();
    int t4 = tid * 4;
    unsigned h0 = hist[t4], h1 = hist[t4 + 1], h2 = hist[t4 + 2], h3 = hist[t4 + 3];
    unsigned th = h0 + h1 + h2 + h3;
    unsigned v = th;
#pragma unroll
    for (int off = 1; off < 64; off <<= 1) {
      unsigned tv = (unsigned)__shfl_down((int)v, off);
      if (lane + off < 64) v += tv;
    }
    if (lane == 0) wtot[wv] = v;
    __syncthreads();
    unsigned add = 0;
    for (int w2 = wv + 1; w2 < 16; w2++) add += wtot[w2];
    unsigned S_t = v + add;
    unsigned S_next = S_t - th;
    if (S_t >= (unsigned)k && S_next < (unsigned)k) {
      unsigned run = S_next; int Bl; unsigned kpl;
      if (run + h3 >= (unsigned)k) { Bl = t4 + 3; kpl = k - run; }
      else { run += h3;
        if (run + h2 >= (unsigned)k) { Bl = t4 + 2; kpl = k - run; }
        else { run += h2;
          if (run + h1 >= (unsigned)k) { Bl = t4 + 1; kpl = k - run; }
          else { run += h1; Bl = t4; kpl = k - run; } } }
      s_B = Bl; s_kp = (int)kpl;
    }
    __syncthreads();
    B = s_B; kp = s_kp; m = (int)hist[B];
    allB = (kp == m);
    fallback = (!allB && m > MAXM);
  }

  float acc = 0.f;
  if (haveNeg && !allB && !fallback) {
    if (tid == 0) s_mc = 0;
    __syncthreads();
#pragma unroll
    for (int c = 0; c < 4; c++) {
#pragma unroll
      for (int f = 0; f < 4; f++) {
        int j = c * 4 + f;
        if (bm[j] == B) {
          unsigned slot = atomicAdd(&s_mc, 1u);
          resv[slot] = vm[j];
          residx[slot] = (4 * (c * 1024 + tid) + f) | (((pmask >> j) & 1u) ? 0x40000000 : 0);
        }
      }
    }
    if (hasTail) {
#pragma unroll
      for (int j = 0; j < 4; j++) {
        if (bt4[j] == B) {
          unsigned slot = atomicAdd(&s_mc, 1u);
          resv[slot] = vt[j];
          residx[slot] = (16384 + tid * 4 + j) | (((tmask >> j) & 1u) ? 0x40000000 : 0);
        }
      }
    }
    __syncthreads();
    for (int i = tid; i < m; i += 1024) {
      float vi = resv[i];
      int pk = residx[i];
      int ii = pk & 0x3FFFFFFF;
      bool posi = (pk & 0x40000000) != 0;
      int rank = 0;
      for (int j = 0; j < m; j++) {
        float vj = resv[j];
        int ij = residx[j] & 0x3FFFFFFF;
        rank += (vj > vi || (vj == vi && ij < ii)) ? 1 : 0;
      }
      if (rank < kp && !posi) acc += vi;
    }
  }

  unsigned T = 0, R = 0, C = 0;
  if (fallback) {
    __shared__ unsigned s_lo, s_hi, fcnt[16];
    if (tid == 0) { s_lo = 0u; s_hi = 0xFFFFFFFFu; }
    __syncthreads();
    for (int it = 0; it < 32; it++) {
      unsigned lo = s_lo, hi = s_hi;
      unsigned mid = lo + ((hi - lo) >> 1) + ((hi - lo) & 1u);
      unsigned c = 0;
#pragma unroll
      for (int j = 0; j < 16; j++) c += (f2key(vm[j]) >= mid) ? 1u : 0u;
      if (hasTail) {
#pragma unroll
        for (int j = 0; j < 4; j++) c += (f2key(vt[j]) >= mid) ? 1u : 0u;
      }
#pragma unroll
      for (int o = 32; o; o >>= 1) c += (unsigned)__shfl_down((int)c, o);
      if (lane == 0) fcnt[wv] = c;
      __syncthreads();
      if (tid == 0) {
        unsigned tot = 0;
        for (int i = 0; i < 16; i++) tot += fcnt[i];
        if (tot >= (unsigned)k) s_lo = mid; else s_hi = mid - 1;
      }
      __syncthreads();
      if (s_lo >= s_hi) break;
    }
    T = s_lo;
    unsigned cg = 0, ce = 0;
#pragma unroll
    for (int j = 0; j < 16; j++) {
      unsigned key = f2key(vm[j]);
      cg += (key > T) ? 1u : 0u;
      ce += (key == T) ? 1u : 0u;
    }
    if (hasTail) {
#pragma unroll
      for (int j = 0; j < 4; j++) {
        unsigned key = f2key(vt[j]);
        cg += (key > T) ? 1u : 0u;
        ce += (key == T) ? 1u : 0u;
      }
    }
#pragma unroll
    for (int o = 32; o; o >>= 1) {
      cg += (unsigned)__shfl_down((int)cg, o);
      ce += (unsigned)__shfl_down((int)ce, o);
    }
    if (lane == 0) { fcnt[wv] = cg; wtot[wv] = ce; }
    __syncthreads();
    if (tid == 0) {
      unsigned tg2 = 0, te = 0;
      for (int i = 0; i < 16; i++) { tg2 += fcnt[i]; te += wtot[i]; }
      fcnt[0] = tg2; wtot[0] = te;
    }
    __syncthreads();
    C = wtot[0];
    R = (unsigned)k - fcnt[0];
    if (C != R && tid < 64) {
      unsigned running = 0;
      for (int base2 = 0; base2 < PN; base2 += 64) {
        int p = base2 + tid;
        bool tie = false, pos = false;
        float v2 = 0.f;
        if (p < PN) { v2 = row[p]; tie = (f2key(v2) == T); pos = prow[p] != 0; }
        unsigned long long mm = __ballot(tie);
        if (tie) {
          unsigned rank = running + (unsigned)__popcll(mm & ((1ull << tid) - 1));
          if (rank < R && !pos) acc += v2;
        }
        running += (unsigned)__popcll(mm);
      }
    }
  }

  unsigned ptc = 0;
#pragma unroll
  for (int j = 0; j < 16; j++) {
    float v2 = vm[j];
    bool pos = (pmask >> j) & 1u;
    if (pos) acc += v2;
    else if (haveNeg) {
      if (!fallback) {
        if (bm[j] > B || (bm[j] == B && allB)) acc += v2;
      } else {
        if (f2key(v2) > T) acc += v2;
      }
    }
    if (fallback && pos && f2key(v2) == T) ptc++;
  }
  if (hasTail) {
#pragma unroll
    for (int j = 0; j < 4; j++) {
      float v2 = vt[j];
      bool pos = (tmask >> j) & 1u;
      if (pos) acc += v2;
      else if (haveNeg) {
        if (!fallback) {
          if (bt4[j] > B || (bt4[j] == B && allB)) acc += v2;
        } else {
          if (f2key(v2) > T) acc += v2;
        }
      }
      if (fallback && pos && f2key(v2) == T) ptc++;
    }
  }
  for (int o = 32; o; o >>= 1) {
    acc += __shfl_down(acc, o);
    ptc += __shfl_down(ptc, o);
  }
  __shared__ float wsum[16];
  __shared__ unsigned wpt[16];
  if (lane == 0) { wsum[wv] = acc; wpt[wv] = ptc; }
  __syncthreads();

  __shared__ float s_rsl, s_rslm;
  __shared__ int s_rnp1;
  if (tid == 0) { s_rsl = 0.f; s_rslm = 0.f; s_rnp1 = 0; }
  __syncthreads();
  if (tid < GX) {
    atomicAdd(&s_rsl, part_l[b * GX + tid]);
    atomicAdd(&s_rslm, part_lm[b * GX + tid]);
    atomicAdd(&s_rnp1, np1_part[b * GX + tid]);
  }
  __syncthreads();

  if (tid == 0) {
    float tot = 0.f; unsigned pt = 0;
    for (int i = 0; i < 16; i++) { tot += wsum[i]; pt += wpt[i]; }
    if (fallback && C == R) tot += (float)(C - pt) * key2f(T);
    atomicAdd(&gacc->sc, tot);
    atomicAdd(&gacc->sl, s_rsl);
    atomicAdd(&gacc->slm, s_rslm);
    atomicAdd(&gacc->np, np);
    atomicAdd(&gacc->np1, s_rnp1);
  }
  __threadfence();
  __shared__ int lastF;
  if (tid == 0) lastF = (atomicAdd(&gacc->ticket, 1u) == (unsigned)(BN - 1)) ? 1 : 0;
  __syncthreads();
  if (lastF && tid == 0) {
    __threadfence();
    float sl = atomicAdd(&gacc->sl, 0.f);
    float slm = atomicAdd(&gacc->slm, 0.f);
    float sc = atomicAdd(&gacc->sc, 0.f);
    int tnp = atomicAdd(&gacc->np, 0);
    int tnp1 = atomicAdd(&gacc->np1, 0);
    float N = fmaxf((float)tnp, 1.f);
    float N1 = fmaxf((float)tnp1, 1.f);
    out[0] = sl / N;
    out[1] = sc / N;
    out[2] = slm / N1;
  }
}

extern "C" void kernel_launch(void* const* d_in, const int* in_sizes, int n_in,
                              void* d_out, int out_size, void* d_ws, size_t ws_size,
                              hipStream_t stream) {
  const float* loc_data = (const float*)d_in[0];
  const float* conf_data = (const float*)d_in[1];
  const float* landm_data = (const float*)d_in[2];
  const float* priors = (const float*)d_in[3];
  const float* targets = (const float*)d_in[4];
  float* out = (float*)d_out;

  char* ws = (char*)d_ws;
  size_t off = 0;
  float* lossc = (float*)(ws + off); off += (size_t)BN * PN * 4;              // 4.30 MB
  unsigned char* btpack = (unsigned char*)(ws + off); off += (size_t)BN * PN; // 1.07 MB
  unsigned char* posf = (unsigned char*)(ws + off); off += (size_t)BN * PN;   // 1.07 MB
  off = (off + 15) & ~(size_t)15;
  unsigned long long* bpp = (unsigned long long*)(ws + off); off += (size_t)BN * ON * 8;
  float* part_l = (float*)(ws + off); off += NBLK * 4;
  float* part_lm = (float*)(ws + off); off += NBLK * 4;
  int* np_part = (int*)(ws + off); off += NBLK * 4;
  int* np1_part = (int*)(ws + off); off += NBLK * 4;
  float4* sbox = (float4*)(ws + off); off += (size_t)PN * 16;
  int* sorig = (int*)(ws + off); off += (size_t)PN * 4;
  int* scell = (int*)(ws + off); off += (size_t)PN * 4;
  int* inv = (int*)(ws + off); off += (size_t)PN * 4;
  unsigned char* pcell = (unsigned char*)(ws + off); off += (size_t)PN;
  off = (off + 15) & ~(size_t)15;
  int* cellOff = (int*)(ws + off); off += 260 * 4;
  unsigned long long* tmask = (unsigned long long*)(ws + off); off += (size_t)BN * NCELL * 8;
  off = (off + 15) & ~(size_t)15;
  unsigned* bhist = (unsigned*)(ws + off); off += (size_t)NCB * NCELL * 4;    // 67.6 KB
  float* gmaxblk = (float*)(ws + off); off += (size_t)NCB * 2 * 4;
  unsigned* gmax = (unsigned*)(ws + off); off += 16;
  GAcc* gacc = (GAcc*)(ws + off); off += sizeof(GAcc);
  // total ~7.3 MB

  k_count<<<NCB, 256, 0, stream>>>(priors, pcell, bhist, gmaxblk, gacc);
  k_scatter<<<NCB + BN, 256, 0, stream>>>(priors, targets, pcell, bhist, gmaxblk, gmax,
                                          sbox, sorig, scell, inv, cellOff, tmask);
  k_pair<<<NBP + NBTT, 256, 0, stream>>>(targets, sbox, sorig, scell, cellOff, gmax,
                                         tmask, btpack, bpp);
  dim3 gbp(GX, BN);
  k_encode<<<gbp, 256, 0, stream>>>(loc_data, conf_data, landm_data, priors, targets,
                                    btpack, inv, bpp, lossc, posf,
                                    part_l, part_lm, np_part, np1_part);
  k_select<<<BN, 1024, 0, stream>>>(lossc, posf, np_part, np1_part, part_l, part_lm,
                                    gacc, out);
}